// Round 1
// 111.423 us; speedup vs baseline: 1.0149x; 1.0149x over previous
//
#include <hip/hip_runtime.h>
#include <math.h>

// Problem constants (from reference)
#define BB 512
#define SS 4096
#define DD 128
#define VV 6
#define KK 409   // max(1, int(4096*0.1))

// R4: single fused kernel. Iteration = 20 dispatches (16 restores + ws fill
// 41us + out fill + 2 kernels); we can only shrink our 2 kernels + 1 gap.
// The per-block redundant MLP recompute costs ~160 KFLOP vs a whole
// dispatch + single-block latency for the old precompute. Weights are read
// from global (L2-hit after first block/XCD, ~108KB working set). Ballot+
// mbcnt replaces the 36-step shfl_up scan (lane-major ordering => exclusive
// offset = sum_i mbcnt64(ballot(vals[i]==t))), wave totals via scalar popc.
// __launch_bounds__(512,4) caps VGPR at 128 => 2 blocks/CU => all 512
// blocks co-resident in one round (prelude paid once, in parallel).

__global__ __launch_bounds__(512, 4) void fused_kernel(
    const int* __restrict__ x,
    const float* __restrict__ emb,
    const float* __restrict__ W1, const float* __restrict__ b1,
    const float* __restrict__ W2, const float* __restrict__ b2,
    const float* __restrict__ W3, const float* __restrict__ b3,
    const float* __restrict__ A1, const float* __restrict__ a1,
    const float* __restrict__ A2, const float* __restrict__ a2,
    const float* __restrict__ C1, const float* __restrict__ c1,
    const float* __restrict__ C2, const float* __restrict__ c2,
    float* __restrict__ pred, float* __restrict__ topk, float* __restrict__ fsc)
{
    __shared__ float sE[VV * DD];
    __shared__ float sb1[64], sb2[32], sa1[64], sa2[DD], sW3[32];
    __shared__ float sh1[VV * 64], sg[VV * 64], sh2[VV * 32];
    __shared__ float sc[VV];
    __shared__ float att_s[VV * DD];
    __shared__ int   waveTot[8 * 8];
    __shared__ float pooled[DD];
    __shared__ float hcls[64];
    __shared__ float sb3;

    const int tid  = threadIdx.x;   // 512
    const int b    = blockIdx.x;
    const int lane = tid & 63;
    const int w    = tid >> 6;      // 0..7

    // x row loads first: the only HBM-latency-critical reads; latency hides
    // under the emb staging + stage1 weight reads below.
    const int base = b * SS + tid * 8;
    const int4* xp = (const int4*)(x + base);
    int4 xv0 = xp[0], xv1 = xp[1];

    // stage emb + small vectors into LDS
    for (int i = tid; i < VV * DD; i += 512) sE[i] = emb[i];
    if (tid < 64)        sb1[tid]       = b1[tid];
    else if (tid < 96)   sb2[tid - 64]  = b2[tid - 64];
    else if (tid < 160)  sa1[tid - 96]  = a1[tid - 96];
    else if (tid < 288)  sa2[tid - 160] = a2[tid - 160];
    else if (tid < 320)  sW3[tid - 288] = W3[tid - 288];
    else if (tid == 320) sb3 = b3[0];
    __syncthreads();

    // stage1: h1[6][64] (importance L1) + g[6][64] (attn L1), weights from
    // global (coalesced 64-wide columns, L2-resident after first block).
    for (int u = tid; u < 2 * VV * 64; u += 512) {
        const int isH = (u < VV * 64) ? 1 : 0;
        const int v = isH ? u : (u - VV * 64);
        const int t = v >> 6, o = v & 63;
        const float* wcol = isH ? W1 : A1;
        float acc = isH ? sb1[o] : sa1[o];
        const float* ev = &sE[t * DD];
        #pragma unroll 8
        for (int d = 0; d < DD; ++d) acc += ev[d] * wcol[d * 64 + o];
        acc = fmaxf(acc, 0.f);
        if (isH) sh1[v] = acc; else sg[v] = acc;
    }

    // token counting via ballot + mbcnt (overlaps stage1's global loads).
    // Sequence order is lane-major within a wave (token idx = tid*8+i), so
    // exclusive offset = sum_i popcount(mask_i & lanemask_lt).
    int vals[8];
    vals[0] = xv0.x; vals[1] = xv0.y; vals[2] = xv0.z; vals[3] = xv0.w;
    vals[4] = xv1.x; vals[5] = xv1.y; vals[6] = xv1.z; vals[7] = xv1.w;

    int excl[VV];
    #pragma unroll
    for (int t = 0; t < VV; ++t) {
        int ex = 0, tot = 0;
        #pragma unroll
        for (int i = 0; i < 8; ++i) {
            unsigned long long mk = __ballot(vals[i] == t);
            ex += (int)__builtin_amdgcn_mbcnt_hi((unsigned)(mk >> 32),
                       __builtin_amdgcn_mbcnt_lo((unsigned)mk, 0u));
            tot += __popcll(mk);   // wave-uniform -> scalar s_bcnt1
        }
        excl[t] = ex;
        if (lane == 0) waveTot[w * 8 + t] = tot;
    }
    __syncthreads();   // covers sh1, sg, waveTot

    // stage2: h2[6][32] (importance L2) + att[6][128] (attn L2)
    for (int u = tid; u < VV * 32 + VV * DD; u += 512) {
        if (u < VV * 32) {
            const int t = u >> 5, o = u & 31;
            float acc = sb2[o];
            #pragma unroll 8
            for (int j = 0; j < 64; ++j) acc += sh1[t * 64 + j] * W2[j * 32 + o];
            sh2[u] = fmaxf(acc, 0.f);
        } else {
            const int v = u - VV * 32;
            const int t = v >> 7, o = v & 127;
            float acc = sa2[o];
            #pragma unroll 8
            for (int j = 0; j < 64; ++j) acc += sg[t * 64 + j] * A2[j * DD + o];
            att_s[v] = acc;
        }
    }

    // cross-wave totals (waveTot valid since last sync; uniform-address
    // LDS reads broadcast, no conflicts)
    int rowTot[VV], woff[VV];
    #pragma unroll
    for (int t = 0; t < VV; ++t) {
        int tot = 0, wo = 0;
        #pragma unroll
        for (int j = 0; j < 8; ++j) {
            int c = waveTot[j * 8 + t];
            tot += c;
            wo += (j < w) ? c : 0;
        }
        rowTot[t] = tot;
        woff[t] = wo;
    }
    __syncthreads();   // covers sh2, att_s

    // stage3: scores (6 sigmoid dots)
    if (tid < VV) {
        float s = sb3;
        #pragma unroll
        for (int j = 0; j < 32; ++j) s += sh2[tid * 32 + j] * sW3[j];
        sc[tid] = 1.f / (1.f + expf(-s));
    }
    __syncthreads();   // sc ready

    // final_scores: LDS gather (<=6 distinct addrs -> broadcast-served)
    {
        float4* op = (float4*)(fsc + base);
        float4 o0, o1;
        o0.x = sc[vals[0]]; o0.y = sc[vals[1]]; o0.z = sc[vals[2]]; o0.w = sc[vals[3]];
        o1.x = sc[vals[4]]; o1.y = sc[vals[5]]; o1.z = sc[vals[6]]; o1.w = sc[vals[7]];
        op[0] = o0; op[1] = o1;
    }

    // token priority (score desc, index asc) — static register indexing only
    float s_reg[VV];
    #pragma unroll
    for (int t = 0; t < VV; ++t) s_reg[t] = sc[t];
    int pri[VV];
    #pragma unroll
    for (int t = 0; t < VV; ++t) {
        int p = 0;
        #pragma unroll
        for (int u = 0; u < VV; ++u)
            p += ((s_reg[u] > s_reg[t]) || ((s_reg[u] == s_reg[t]) && (u < t))) ? 1 : 0;
        pri[t] = p;
    }
    int start[VV], m[VV];
    #pragma unroll
    for (int t = 0; t < VV; ++t) {
        int cb = 0;
        #pragma unroll
        for (int u = 0; u < VV; ++u)
            cb += (pri[u] < pri[t]) ? rowTot[u] : 0;
        int mm = KK - cb;
        mm = (mm < 0) ? 0 : mm;
        mm = (mm > rowTot[t]) ? rowTot[t] : mm;
        m[t] = mm;
        start[t] = cb + woff[t] + excl[t];
    }

    // emit selected indices
    {
        float* trow = topk + b * KK;
        #pragma unroll
        for (int t = 0; t < VV; ++t) {
            int pos = start[t];
            #pragma unroll
            for (int i = 0; i < 8; ++i) {
                if (vals[i] == t) {
                    if (pos < KK) trow[pos] = (float)(tid * 8 + i);
                    pos++;
                }
            }
        }
    }

    // pooled + classifier
    if (tid < DD) {
        float acc = 0.f;
        #pragma unroll
        for (int t = 0; t < VV; ++t) acc += (float)m[t] * att_s[t * DD + tid];
        pooled[tid] = acc * (1.0f / (float)KK);
    }
    __syncthreads();
    if (tid < 64) {
        float acc = c1[tid];
        #pragma unroll 8
        for (int d = 0; d < DD; ++d) acc += pooled[d] * C1[d * 64 + tid];
        hcls[tid] = fmaxf(acc, 0.f);
    }
    __syncthreads();
    if (tid == 0) {
        float s = c2[0];
        #pragma unroll 8
        for (int j = 0; j < 64; ++j) s += hcls[j] * C2[j];
        pred[b] = 1.f / (1.f + expf(-s));
    }
}

extern "C" void kernel_launch(void* const* d_in, const int* in_sizes, int n_in,
                              void* d_out, int out_size, void* d_ws, size_t ws_size,
                              hipStream_t stream)
{
    (void)in_sizes; (void)n_in; (void)out_size; (void)d_ws; (void)ws_size;
    const int*   x   = (const int*)d_in[0];
    const float* emb = (const float*)d_in[1];
    const float* W1  = (const float*)d_in[2];
    const float* b1  = (const float*)d_in[3];
    const float* W2  = (const float*)d_in[4];
    const float* b2  = (const float*)d_in[5];
    const float* W3  = (const float*)d_in[6];
    const float* b3  = (const float*)d_in[7];
    const float* A1  = (const float*)d_in[8];
    const float* a1  = (const float*)d_in[9];
    const float* A2  = (const float*)d_in[10];
    const float* a2  = (const float*)d_in[11];
    const float* C1  = (const float*)d_in[12];
    const float* c1  = (const float*)d_in[13];
    const float* C2  = (const float*)d_in[14];
    const float* c2  = (const float*)d_in[15];

    float* out  = (float*)d_out;
    float* pred = out;                 // [B]
    float* topk = out + BB;            // [B,K] (indices as float32 — exact)
    float* fsc  = out + BB + BB*KK;    // [B,S]

    fused_kernel<<<BB, 512, 0, stream>>>(x, emb, W1, b1, W2, b2, W3, b3,
                                         A1, a1, A2, a2, C1, c1, C2, c2,
                                         pred, topk, fsc);
}